// Round 5
// baseline (204.542 us; speedup 1.0000x reference)
//
#include <hip/hip_runtime.h>
#include <hip/hip_bf16.h>
#include <math.h>

#define B_  64
#define D_  512
#define NQ  8
#define NL  4

typedef __bf16 bf16;
typedef float  f32x4  __attribute__((ext_vector_type(4)));
typedef bf16   bf16x8 __attribute__((ext_vector_type(8)));

__device__ __forceinline__ void async_load16(const bf16* g, bf16* l) {
    __builtin_amdgcn_global_load_lds(
        (const __attribute__((address_space(1))) void*)g,
        (__attribute__((address_space(3))) void*)l, 16, 0, 0);
}

// ---------------------------------------------------------------------------
// fp32 -> bf16 bulk convert (8 elems / thread)
// ---------------------------------------------------------------------------
__global__ __launch_bounds__(256) void convert_kernel(const float* __restrict__ src,
                                                      bf16* __restrict__ dst, int n8) {
    int i = blockIdx.x * 256 + threadIdx.x;
    if (i < n8) {
        const float4 v0 = *(const float4*)(src + (size_t)i * 8);
        const float4 v1 = *(const float4*)(src + (size_t)i * 8 + 4);
        bf16x8 p;
        p[0] = (bf16)v0.x; p[1] = (bf16)v0.y; p[2] = (bf16)v0.z; p[3] = (bf16)v0.w;
        p[4] = (bf16)v1.x; p[5] = (bf16)v1.y; p[6] = (bf16)v1.z; p[7] = (bf16)v1.w;
        *(bf16x8*)(dst + (size_t)i * 8) = p;
    }
}

// ---------------------------------------------------------------------------
// Pipelined full-DMA NT GEMM:
//   C[b][m][n] = (gelu?)( sum_k A[m][k] * Bv[b][n][k] (+ bias[n]) )
// Double-buffered LDS; per K-step each wave issues 8 global_load_lds (16B).
// AITER-style loop: issue k+1, s_waitcnt vmcnt(8) (only step k drained),
// raw s_barrier (no vmcnt(0) drain), compute, s_barrier.
// Chunk-XOR swizzle: LDS slot s of row r holds global chunk s^(r&7).
// ---------------------------------------------------------------------------
template <int GELU>
__global__ __launch_bounds__(256) void gemm_nt_pipe(const bf16* __restrict__ A,
                                                    const bf16* __restrict__ Bv,
                                                    const float* __restrict__ bias,
                                                    void* __restrict__ Cout) {
    __shared__ bf16 SA[2][128 * 64];   // [buf][row*64 + k], 128 B rows, XOR-swizzled
    __shared__ bf16 SB[2][128 * 64];
    const int b    = blockIdx.y;
    const int tile = blockIdx.x;
    const int m0   = (tile >> 2) * 128;
    const int n0   = (tile & 3) * 128;
    const int t    = threadIdx.x;
    const int lane = t & 63;
    const int w    = t >> 6;
    const int wr   = (w >> 1) * 64;
    const int wc   = (w & 1) * 64;
    const int l15  = lane & 15;
    const int quad = lane >> 4;

    f32x4 acc[4][4];
    for (int i = 0; i < 4; i++)
        for (int j = 0; j < 4; j++) acc[i][j] = (f32x4)(0.0f);

    const bf16* Bb = Bv + (size_t)b * D_ * D_;

    // staging geometry: one issue = 64 lanes x 16B = 8 rows of 128 B.
    const int rl = lane >> 3;              // row within issue (0..7)
    const int ck = (lane & 7) ^ rl;        // global chunk for this lane's slot

    // 8 DMA insts per wave per step (4 j x {A,B})
    #define ISSUE_STEP(KK, BUF)                                                          \
        {                                                                                \
            const int k0_ = (KK) * 64;                                                   \
            _Pragma("unroll")                                                            \
            for (int j = 0; j < 4; j++) {                                                \
                int rbase = w * 32 + j * 8;                                              \
                async_load16(A  + (size_t)(m0 + rbase + rl) * D_ + k0_ + ck * 8,         \
                             &SA[BUF][rbase * 64]);                                      \
                async_load16(Bb + (size_t)(n0 + rbase + rl) * D_ + k0_ + ck * 8,         \
                             &SB[BUF][rbase * 64]);                                      \
            }                                                                            \
        }

    ISSUE_STEP(0, 0);

    #pragma unroll
    for (int k = 0; k < 8; k++) {
        const int cur = k & 1;
        if (k < 7) {
            ISSUE_STEP(k + 1, (k + 1) & 1);
            asm volatile("s_waitcnt vmcnt(8)" ::: "memory");
        } else {
            asm volatile("s_waitcnt vmcnt(0)" ::: "memory");
        }
        __builtin_amdgcn_s_barrier();   // all waves' step-k loads have landed

        #pragma unroll
        for (int kk = 0; kk < 2; kk++) {
            bf16x8 af[4], bfr[4];
            #pragma unroll
            for (int mt = 0; mt < 4; mt++) {
                int row = wr + mt * 16 + l15;
                int s   = (kk * 4 + quad) ^ (l15 & 7);
                af[mt] = *(const bf16x8*)&SA[cur][row * 64 + s * 8];
            }
            #pragma unroll
            for (int nt = 0; nt < 4; nt++) {
                int row = wc + nt * 16 + l15;
                int s   = (kk * 4 + quad) ^ (l15 & 7);
                bfr[nt] = *(const bf16x8*)&SB[cur][row * 64 + s * 8];
            }
            #pragma unroll
            for (int mt = 0; mt < 4; mt++)
                #pragma unroll
                for (int nt = 0; nt < 4; nt++)
                    acc[mt][nt] = __builtin_amdgcn_mfma_f32_16x16x32_bf16(af[mt], bfr[nt], acc[mt][nt], 0, 0, 0);
        }
        __builtin_amdgcn_s_barrier();   // reads of buf[cur] done before k+2 overwrites
    }
    #undef ISSUE_STEP

    if (GELU == 0) {
        bf16* Cb = (bf16*)Cout + (size_t)b * D_ * D_;
        for (int mt = 0; mt < 4; mt++) {
            int row = m0 + wr + mt * 16 + quad * 4;
            for (int nt = 0; nt < 4; nt++) {
                int col = n0 + wc + nt * 16 + l15;
                for (int r = 0; r < 4; r++)
                    Cb[(size_t)(row + r) * D_ + col] = (bf16)acc[mt][nt][r];
            }
        }
    } else {
        float* Cb = (float*)Cout + (size_t)b * D_ * D_;
        for (int mt = 0; mt < 4; mt++) {
            int row = m0 + wr + mt * 16 + quad * 4;
            for (int nt = 0; nt < 4; nt++) {
                int col = n0 + wc + nt * 16 + l15;
                float bv = bias[col];
                for (int r = 0; r < 4; r++) {
                    float v = acc[mt][nt][r] + bv;
                    Cb[(size_t)(row + r) * D_ + col] = 0.5f * v * (1.0f + erff(v * 0.70710678118654752f));
                }
            }
        }
    }
}

// ---------------------------------------------------------------------------
// Quantum: one wave per batch element (validated R2-R4).
// ---------------------------------------------------------------------------
__global__ __launch_bounds__(64) void quantum_kernel(float* __restrict__ out,
                                                     const float* __restrict__ pre_w,
                                                     const float* __restrict__ pre_b,
                                                     const float* __restrict__ post_w,
                                                     const float* __restrict__ post_b,
                                                     const float* __restrict__ qw) {
    const int b = blockIdx.x;
    const int l = threadIdx.x;
    float* row0 = out + (size_t)b * D_ * D_;

    float tg[8];
    #pragma unroll
    for (int j = 0; j < 8; j++) tg[j] = row0[l + 64 * j];

    float ang[NQ];
    #pragma unroll
    for (int q = 0; q < NQ; q++) {
        float s = 0.f;
        #pragma unroll
        for (int j = 0; j < 8; j++) s += tg[j] * pre_w[q * D_ + l + 64 * j];
        #pragma unroll
        for (int m = 32; m >= 1; m >>= 1) s += __shfl_xor(s, m, 64);
        ang[q] = tanhf(s + pre_b[q]) * 3.14159265358979323846f;
    }

    float cw[NQ], sw[NQ];
    #pragma unroll
    for (int w = 0; w < NQ; w++) { cw[w] = cosf(0.5f * ang[w]); sw[w] = sinf(0.5f * ang[w]); }
    float re[4], im[4];
    #pragma unroll
    for (int r = 0; r < 4; r++) {
        int idx = l * 4 + r;
        float a = 1.f;
        #pragma unroll
        for (int w = 0; w < NQ; w++) a *= ((idx >> (7 - w)) & 1) ? sw[w] : cw[w];
        re[r] = a; im[r] = 0.f;
    }

    for (int lay = 0; lay < NL; lay++) {
        #pragma unroll
        for (int w = 0; w < 6; w++) {
            float th = 0.5f * qw[lay * NQ + w];
            float c = cosf(th), s = sinf(th);
            int m = 1 << (5 - w);
            #pragma unroll
            for (int r = 0; r < 4; r++) {
                float pre_ = __shfl_xor(re[r], m, 64);
                float pim_ = __shfl_xor(im[r], m, 64);
                re[r] = c * re[r] + s * pim_;
                im[r] = c * im[r] - s * pre_;
            }
        }
        {   // qubit 6 (bit 1): partner r^2
            float th = 0.5f * qw[lay * NQ + 6];
            float c = cosf(th), s = sinf(th);
            float or0 = re[0], or1 = re[1], or2 = re[2], or3 = re[3];
            float oi0 = im[0], oi1 = im[1], oi2 = im[2], oi3 = im[3];
            re[0] = c * or0 + s * oi2;  im[0] = c * oi0 - s * or2;
            re[1] = c * or1 + s * oi3;  im[1] = c * oi1 - s * or3;
            re[2] = c * or2 + s * oi0;  im[2] = c * oi2 - s * or0;
            re[3] = c * or3 + s * oi1;  im[3] = c * oi3 - s * or1;
        }
        {   // qubit 7 (bit 0): partner r^1
            float th = 0.5f * qw[lay * NQ + 7];
            float c = cosf(th), s = sinf(th);
            float or0 = re[0], or1 = re[1], or2 = re[2], or3 = re[3];
            float oi0 = im[0], oi1 = im[1], oi2 = im[2], oi3 = im[3];
            re[0] = c * or0 + s * oi1;  im[0] = c * oi0 - s * or1;
            re[1] = c * or1 + s * oi0;  im[1] = c * oi1 - s * or0;
            re[2] = c * or2 + s * oi3;  im[2] = c * oi2 - s * or3;
            re[3] = c * or3 + s * oi2;  im[3] = c * oi3 - s * or2;
        }
        #pragma unroll
        for (int w = 0; w < 5; w++) {
            int cb = 7 - w, tb = 6 - w;
            int tm = 1 << (tb - 2);
            bool ctl = (l >> (cb - 2)) & 1;
            #pragma unroll
            for (int r = 0; r < 4; r++) {
                float pre_ = __shfl_xor(re[r], tm, 64);
                float pim_ = __shfl_xor(im[r], tm, 64);
                re[r] = ctl ? pre_ : re[r];
                im[r] = ctl ? pim_ : im[r];
            }
        }
        {   // (5,6)
            bool ctl = l & 1;
            float t0 = re[0], t1 = re[1], t2 = re[2], t3 = re[3];
            float u0 = im[0], u1 = im[1], u2 = im[2], u3 = im[3];
            re[0] = ctl ? t2 : t0;  re[1] = ctl ? t3 : t1;
            re[2] = ctl ? t0 : t2;  re[3] = ctl ? t1 : t3;
            im[0] = ctl ? u2 : u0;  im[1] = ctl ? u3 : u1;
            im[2] = ctl ? u0 : u2;  im[3] = ctl ? u1 : u3;
        }
        {   // (6,7)
            float t2 = re[2], t3 = re[3], u2 = im[2], u3 = im[3];
            re[2] = t3; re[3] = t2; im[2] = u3; im[3] = u2;
        }
        {   // (7,0)
            #pragma unroll
            for (int r = 0; r < 4; r++) {
                float pre_ = __shfl_xor(re[r], 32, 64);
                float pim_ = __shfl_xor(im[r], 32, 64);
                if (r & 1) { re[r] = pre_; im[r] = pim_; }
            }
        }
    }

    float pr[4];
    #pragma unroll
    for (int r = 0; r < 4; r++) pr[r] = re[r] * re[r] + im[r] * im[r];
    float z[NQ];
    #pragma unroll
    for (int q = 0; q < NQ; q++) {
        int bit = 7 - q;
        float s = 0.f;
        #pragma unroll
        for (int r = 0; r < 4; r++) {
            int idx = l * 4 + r;
            s += ((idx >> bit) & 1) ? -pr[r] : pr[r];
        }
        #pragma unroll
        for (int m = 32; m >= 1; m >>= 1) s += __shfl_xor(s, m, 64);
        z[q] = s;
    }

    #pragma unroll
    for (int j = 0; j < 8; j++) {
        int h = l + 64 * j;
        float v = post_b[h];
        #pragma unroll
        for (int q = 0; q < NQ; q++) v += z[q] * post_w[h * NQ + q];
        row0[h] = v;
    }
}

// ---------------------------------------------------------------------------
extern "C" void kernel_launch(void* const* d_in, const int* in_sizes, int n_in,
                              void* d_out, int out_size, void* d_ws, size_t ws_size,
                              hipStream_t stream) {
    const float* x        = (const float*)d_in[0];
    const float* norm_adj = (const float*)d_in[1];
    const float* W_gcn_w  = (const float*)d_in[2];
    const float* W_gcn_b  = (const float*)d_in[3];
    const float* pre_w    = (const float*)d_in[4];
    const float* pre_b    = (const float*)d_in[5];
    const float* post_w   = (const float*)d_in[6];
    const float* post_b   = (const float*)d_in[7];
    const float* q_w      = (const float*)d_in[8];
    float* out = (float*)d_out;

    bf16* xbf = (bf16*)d_out;                    // dead space until gemm2 writes
    bf16* Yt  = (bf16*)d_ws;                     // 32 MiB
    const size_t MB32 = (size_t)32 * 1024 * 1024;
    bf16* Wbf   = (bf16*)((char*)d_ws + MB32);   // ws_size >= 34 MB (verified R4 path taken)
    bf16* adjbf = Wbf + D_ * D_;

    const int n8_x = B_ * D_ * D_ / 8;
    const int n8_m = D_ * D_ / 8;
    convert_kernel<<<(n8_m + 255) / 256, 256, 0, stream>>>(W_gcn_w, Wbf, n8_m);
    convert_kernel<<<(n8_m + 255) / 256, 256, 0, stream>>>(norm_adj, adjbf, n8_m);
    convert_kernel<<<(n8_x + 255) / 256, 256, 0, stream>>>(x, xbf, n8_x);

    dim3 grid(16, B_);
    // Yt[b][g][j] = sum_h W[g][h] * x[b][j][h]
    gemm_nt_pipe<0><<<grid, 256, 0, stream>>>(Wbf, xbf, nullptr, (void*)Yt);
    // out[b][i][g] = gelu( sum_j adj[i][j] * Yt[b][g][j] + bias[g] )
    gemm_nt_pipe<1><<<grid, 256, 0, stream>>>(adjbf, Yt, W_gcn_b, (void*)out);

    quantum_kernel<<<B_, 64, 0, stream>>>(out, pre_w, pre_b, post_w, post_b, q_w);
}